// Round 4
// baseline (187.263 us; speedup 1.0000x reference)
//
#include <hip/hip_runtime.h>
#include <hip/hip_bf16.h>

#define BATCH 8
#define CTX   2048
#define EMB   1024
#define HD    128
#define VSTR  2080   // Vt row stride (elems): 4160B = 65 cache lines -> L1 set spread

using bf16x8 = __attribute__((ext_vector_type(8))) short;
using fx4    = __attribute__((ext_vector_type(4))) float;

__device__ __forceinline__ ushort f2bf(float f) {
    union { float f; unsigned u; } v; v.f = f;
    unsigned u = v.u;
    u += 0x7fffu + ((u >> 16) & 1u);   // RNE
    return (ushort)(u >> 16);
}

__device__ __forceinline__ unsigned cvtpk(float a, float b) {
    unsigned r;
    asm("v_cvt_pk_bf16_f32 %0, %1, %2" : "=v"(r) : "v"(a), "v"(b));
    return r;
}

__device__ __forceinline__ void gload16(const void* g, void* l) {
    __builtin_amdgcn_global_load_lds(
        (const __attribute__((address_space(1))) unsigned*)g,
        (__attribute__((address_space(3))) unsigned*)l, 16, 0, 0);
}

// ---------------- kernel 1: W (E,H) fp32 -> Wt (3,H,E) bf16 ----------------
__global__ void wt_kernel(const float* __restrict__ Wq, const float* __restrict__ Wk,
                          const float* __restrict__ Wv, ushort* __restrict__ Wt) {
    int idx = blockIdx.x * blockDim.x + threadIdx.x;      // [3][HD][EMB]
    int e = idx % EMB;
    int h = (idx / EMB) % HD;
    int w = idx / (EMB * HD);
    const float* W = (w == 0) ? Wq : (w == 1) ? Wk : Wv;
    Wt[idx] = f2bf(W[e * HD + h]);
}

// ---------------- kernel 2: tiled projection GEMM ---------------------------
__global__ __launch_bounds__(256) void proj_kernel(
        const float* __restrict__ x, const ushort* __restrict__ Wt,
        ushort* __restrict__ q, ushort* __restrict__ k, ushort* __restrict__ vt) {
    __shared__ __align__(16) float  As[128 * 64];   // 32 KB
    __shared__ __align__(16) ushort Bs[128 * 64];   // 16 KB

    const int t    = threadIdx.x;
    const int wave = t >> 6;
    const int lane = t & 63;
    const int lo = lane & 15, hi = lane >> 4;
    const int wr = wave >> 1, wc = wave & 1;
    const int bn   = blockIdx.x;                    // 0=q, 1=k, 2=v
    const int brow = blockIdx.y * 128;

    const char* Ab = (const char*)As;
    const char* Bb = (const char*)Bs;

    fx4 acc[4][4];
#pragma unroll
    for (int m2 = 0; m2 < 4; m2++)
#pragma unroll
        for (int n = 0; n < 4; n++) acc[m2][n] = fx4{0.f, 0.f, 0.f, 0.f};

    const int arow_s = t >> 4;
    const int acol_s = ((t & 15) ^ ((t >> 4) & 7)) << 2;
    const int brow_s = t >> 3;
    const int bcol_s = ((t & 7) ^ ((t >> 3) & 7)) << 3;
    const int ldsbase = wave * 1024;

    for (int k0 = 0; k0 < EMB; k0 += 64) {
#pragma unroll
        for (int r = 0; r < 8; r++)
            gload16(x + (size_t)(brow + r * 16 + arow_s) * EMB + k0 + acol_s,
                    (char*)As + r * 4096 + ldsbase);
#pragma unroll
        for (int r = 0; r < 4; r++)
            gload16(Wt + (size_t)(bn * 128 + r * 32 + brow_s) * EMB + k0 + bcol_s,
                    (char*)Bs + r * 4096 + ldsbase);
        __syncthreads();

#pragma unroll
        for (int ks = 0; ks < 2; ks++) {
            bf16x8 af[4], bfr[4];
#pragma unroll
            for (int m2 = 0; m2 < 4; m2++) {
                const int rowA = wr * 64 + m2 * 16 + lo;
                const unsigned sw = (rowA & 7) << 4;
                const unsigned ub = rowA * 256 + ks * 128 + hi * 32;
                fx4 a0 = *(const fx4*)(Ab + (ub ^ sw));
                fx4 a1 = *(const fx4*)(Ab + ((ub + 16) ^ sw));
                union { unsigned u[4]; bf16x8 v; } pk;
                pk.u[0] = cvtpk(a0[0], a0[1]);
                pk.u[1] = cvtpk(a0[2], a0[3]);
                pk.u[2] = cvtpk(a1[0], a1[1]);
                pk.u[3] = cvtpk(a1[2], a1[3]);
                af[m2] = pk.v;
            }
#pragma unroll
            for (int n = 0; n < 4; n++) {
                const int rowB = wc * 64 + n * 16 + lo;
                const unsigned ub = rowB * 128 + ks * 64 + hi * 16;
                bfr[n] = *(const bf16x8*)(Bb + (ub ^ ((rowB & 7) << 4)));
            }
#pragma unroll
            for (int m2 = 0; m2 < 4; m2++)
#pragma unroll
                for (int n = 0; n < 4; n++)
                    acc[m2][n] = __builtin_amdgcn_mfma_f32_16x16x32_bf16(af[m2], bfr[n], acc[m2][n], 0, 0, 0);
        }
        __syncthreads();
    }

    const float qscale = 0.03125f;   // 1/sqrt(1024)
#pragma unroll
    for (int m2 = 0; m2 < 4; m2++) {
#pragma unroll
        for (int n = 0; n < 4; n++) {
            const int c = wc * 64 + n * 16 + lo;
#pragma unroll
            for (int j = 0; j < 4; j++) {
                const int r = brow + wr * 64 + m2 * 16 + hi * 4 + j;
                if (bn == 0)      q[(size_t)r * HD + c] = f2bf(acc[m2][n][j] * qscale);
                else if (bn == 1) k[(size_t)r * HD + c] = f2bf(acc[m2][n][j]);
                else {
                    const int bb = r >> 11, cc = r & (CTX - 1);
                    vt[((size_t)bb * HD + c) * VSTR + cc] = f2bf(acc[m2][n][j]);
                }
            }
        }
    }
}

// ---------------- kernel 3: causal flash attention ---------------------------
// Flat 512-block grid; xcd=id&7 chunking puts one batch per XCD (K/V L2-res).
// 8 waves: wq = q sub-group (16 rows), wk = KV quarter (it = wk, wk+4, ...).
// Defer-max softmax (no cross-lane in fast path); 3-partial merge via LDS.
__global__ __launch_bounds__(512, 4) void attn_kernel(
        const ushort* __restrict__ q, const ushort* __restrict__ k,
        const ushort* __restrict__ vt, float* __restrict__ out) {
    __shared__ __align__(16) char p_lds[8][2048];       // P tile, XOR-swizzled
    __shared__ float om_lds[2][3][16][129];             // partner O partials
    __shared__ float ml_lds[2][3][2][16];               // partner m / l

    const int id   = blockIdx.x;
    const int xcd  = id & 7, pos = id >> 3;
    const int virt = xcd * 64 + pos;                    // one batch per XCD
    const int b    = virt >> 6;
    const int qt   = 63 - (virt & 63);                  // longest tiles first
    const int wave = threadIdx.x >> 6;
    const int lane = threadIdx.x & 63;
    const int lo = lane & 15, hi = lane >> 4;
    const int wq = wave & 1, wk = wave >> 1;            // wk in [0,4)
    const int q0 = qt * 32 + wq * 16;

    const ushort* qb = q  + (size_t)b * CTX * HD;
    const ushort* kb = k  + (size_t)b * CTX * HD;
    const ushort* vb = vt + (size_t)b * HD * VSTR;

    bf16x8 qf[4];
#pragma unroll
    for (int ks = 0; ks < 4; ks++)
        qf[ks] = *(const bf16x8*)(qb + (q0 + lo) * HD + ks * 32 + hi * 8);

    fx4 o[8];
#pragma unroll
    for (int h = 0; h < 8; h++) o[h] = fx4{0.f, 0.f, 0.f, 0.f};
    float m[4], l[4];
#pragma unroll
    for (int j = 0; j < 4; j++) { m[j] = 0.f; l[j] = 0.f; }

    const int nkv = (q0 + 15) / 64 + 1;
    for (int it = wk; it < nkv; it += 4) {
        const int kv0 = it * 64;
        // ---- V prefetch first (independent, max overlap) ----
        bf16x8 vf[8][2];
#pragma unroll
        for (int h = 0; h < 8; h++)
#pragma unroll
            for (int kk = 0; kk < 2; kk++)
                vf[h][kk] = *(const bf16x8*)(vb + (h * 16 + lo) * VSTR + kv0 + kk * 32 + hi * 8);

        // ---- S = Q K^T ----
        fx4 s[4];
#pragma unroll
        for (int n = 0; n < 4; n++) s[n] = fx4{0.f, 0.f, 0.f, 0.f};
        __builtin_amdgcn_s_setprio(1);
#pragma unroll
        for (int n = 0; n < 4; n++) {
#pragma unroll
            for (int ks = 0; ks < 4; ks++) {
                bf16x8 kf = *(const bf16x8*)(kb + (kv0 + n * 16 + lo) * HD + ks * 32 + hi * 8);
                s[n] = __builtin_amdgcn_mfma_f32_16x16x32_bf16(qf[ks], kf, s[n], 0, 0, 0);
            }
        }
        __builtin_amdgcn_s_setprio(0);

        const bool diag = (kv0 + 64 > q0);
        // ---- mask + overflow check (lane-local) ----
        float pmax[4];
        int allok = 1;
#pragma unroll
        for (int j = 0; j < 4; j++) {
            const int r = q0 + hi * 4 + j;
            if (diag) {
#pragma unroll
                for (int n = 0; n < 4; n++)
                    if ((kv0 + n * 16 + lo) > r) s[n][j] = -INFINITY;
            }
            pmax[j] = fmaxf(fmaxf(s[0][j], s[1][j]), fmaxf(s[2][j], s[3][j]));
            allok &= (pmax[j] <= m[j] + 16.0f);
        }
        if (!__all(allok)) {
            // slow path (diag tiles / rare growth): full reduce + rescale
#pragma unroll
            for (int j = 0; j < 4; j++) {
                float mx = pmax[j];
                mx = fmaxf(mx, __shfl_xor(mx, 1));
                mx = fmaxf(mx, __shfl_xor(mx, 2));
                mx = fmaxf(mx, __shfl_xor(mx, 4));
                mx = fmaxf(mx, __shfl_xor(mx, 8));
                const float mn = fmaxf(m[j], mx);
                const float f  = __expf(m[j] - mn);
                l[j] *= f;
#pragma unroll
                for (int h = 0; h < 8; h++) o[h][j] *= f;
                m[j] = mn;
            }
        }
        // ---- fast exp + lane-local l + P pack ----
#pragma unroll
        for (int j = 0; j < 4; j++) {
            float sum = 0.f;
#pragma unroll
            for (int n = 0; n < 4; n++) {
                const float p = __expf(s[n][j] - m[j]);
                s[n][j] = p;
                sum += p;
            }
            l[j] += sum;
            const int row = hi * 4 + j;
            const unsigned sw = (row & 7) << 4;
#pragma unroll
            for (int n = 0; n < 4; n++) {
                const unsigned cb = (unsigned)((n * 16 + lo) * 2);
                *(ushort*)(p_lds[wave] + row * 128 + (cb ^ sw)) = f2bf(s[n][j]);
            }
        }
        asm volatile("" ::: "memory");
        // ---- PV ----
        bf16x8 pa[2];
#pragma unroll
        for (int kk = 0; kk < 2; kk++) {
            const unsigned ub = (unsigned)(kk * 64 + hi * 16);
            pa[kk] = *(const bf16x8*)(p_lds[wave] + lo * 128 + (ub ^ ((lo & 7) << 4)));
        }
        __builtin_amdgcn_s_setprio(1);
#pragma unroll
        for (int h = 0; h < 8; h++)
#pragma unroll
            for (int kk = 0; kk < 2; kk++)
                o[h] = __builtin_amdgcn_mfma_f32_16x16x32_bf16(pa[kk], vf[h][kk], o[h], 0, 0, 0);
        __builtin_amdgcn_s_setprio(0);
    }

    // ---- one-time cross-lane l reduce ----
#pragma unroll
    for (int j = 0; j < 4; j++) {
        l[j] += __shfl_xor(l[j], 1);
        l[j] += __shfl_xor(l[j], 2);
        l[j] += __shfl_xor(l[j], 4);
        l[j] += __shfl_xor(l[j], 8);
    }

    // ---- merge the four KV quarters + write out ----
    if (wk > 0) {
#pragma unroll
        for (int j = 0; j < 4; j++) {
            const int row = hi * 4 + j;
            if (lo == 0) { ml_lds[wq][wk - 1][0][row] = m[j]; ml_lds[wq][wk - 1][1][row] = l[j]; }
#pragma unroll
            for (int h = 0; h < 8; h++) om_lds[wq][wk - 1][row][h * 16 + lo] = o[h][j];
        }
    }
    __syncthreads();
    if (wk == 0) {
        float* ob = out + ((size_t)b * CTX + q0) * HD;
#pragma unroll
        for (int j = 0; j < 4; j++) {
            const int row = hi * 4 + j;
            float mp[3], lp[3];
            float mt = m[j];
#pragma unroll
            for (int p = 0; p < 3; p++) {
                mp[p] = ml_lds[wq][p][0][row];
                lp[p] = ml_lds[wq][p][1][row];
                mt = fmaxf(mt, mp[p]);
            }
            const float f0 = __expf(m[j] - mt);
            float fp[3];
#pragma unroll
            for (int p = 0; p < 3; p++) fp[p] = __expf(mp[p] - mt);
            const float inv = 1.0f / (l[j] * f0 + lp[0] * fp[0] + lp[1] * fp[1] + lp[2] * fp[2]);
#pragma unroll
            for (int h = 0; h < 8; h++) {
                float acc = o[h][j] * f0;
#pragma unroll
                for (int p = 0; p < 3; p++)
                    acc += om_lds[wq][p][row][h * 16 + lo] * fp[p];
                ob[row * HD + h * 16 + lo] = acc * inv;
            }
        }
    }
}

extern "C" void kernel_launch(void* const* d_in, const int* in_sizes, int n_in,
                              void* d_out, int out_size, void* d_ws, size_t ws_size,
                              hipStream_t stream) {
    const float* x  = (const float*)d_in[0];
    const float* Wq = (const float*)d_in[1];
    const float* Wk = (const float*)d_in[2];
    const float* Wv = (const float*)d_in[3];

    // ws: Wt 768KB | q 4MB | k 4MB | Vt (padded) 4.06MB  -> 12.8MB total
    ushort* Wt = (ushort*)d_ws;
    ushort* qw = (ushort*)((char*)d_ws + 786432);
    ushort* kw = qw + (size_t)BATCH * CTX * HD;
    ushort* vw = kw + (size_t)BATCH * CTX * HD;

    wt_kernel<<<(3 * HD * EMB) / 256, 256, 0, stream>>>(Wq, Wk, Wv, Wt);
    proj_kernel<<<dim3(3, 128), 256, 0, stream>>>(x, Wt, qw, kw, vw);
    attn_kernel<<<512, 512, 0, stream>>>(qw, kw, vw, (float*)d_out);
}

// Round 5
// 116.403 us; speedup vs baseline: 1.6087x; 1.6087x over previous
//
#include <hip/hip_runtime.h>
#include <hip/hip_bf16.h>

#define BATCH 8
#define CTX   2048
#define EMB   1024
#define HD    128
#define VSTR  2080   // Vt row stride (elems)

using bf16x8 = __attribute__((ext_vector_type(8))) short;
using fx4    = __attribute__((ext_vector_type(4))) float;

__device__ __forceinline__ ushort f2bf(float f) {
    union { float f; unsigned u; } v; v.f = f;
    unsigned u = v.u;
    u += 0x7fffu + ((u >> 16) & 1u);   // RNE
    return (ushort)(u >> 16);
}

__device__ __forceinline__ unsigned cvtpk(float a, float b) {
    unsigned r;
    asm("v_cvt_pk_bf16_f32 %0, %1, %2" : "=v"(r) : "v"(a), "v"(b));
    return r;
}

__device__ __forceinline__ void gload16(const void* g, void* l) {
    __builtin_amdgcn_global_load_lds(
        (const __attribute__((address_space(1))) unsigned*)g,
        (__attribute__((address_space(3))) unsigned*)l, 16, 0, 0);
}

// ---------------- kernel 1: W (E,H) fp32 -> Wt (3,H,E) bf16 ----------------
__global__ void wt_kernel(const float* __restrict__ Wq, const float* __restrict__ Wk,
                          const float* __restrict__ Wv, ushort* __restrict__ Wt) {
    int idx = blockIdx.x * blockDim.x + threadIdx.x;      // [3][HD][EMB]
    int e = idx % EMB;
    int h = (idx / EMB) % HD;
    int w = idx / (EMB * HD);
    const float* W = (w == 0) ? Wq : (w == 1) ? Wk : Wv;
    Wt[idx] = f2bf(W[e * HD + h]);
}

// ---------------- kernel 2: tiled projection GEMM ---------------------------
__global__ __launch_bounds__(256) void proj_kernel(
        const float* __restrict__ x, const ushort* __restrict__ Wt,
        ushort* __restrict__ q, ushort* __restrict__ k, ushort* __restrict__ vt) {
    __shared__ __align__(16) float  As[128 * 64];   // 32 KB
    __shared__ __align__(16) ushort Bs[128 * 64];   // 16 KB

    const int t    = threadIdx.x;
    const int wave = t >> 6;
    const int lane = t & 63;
    const int lo = lane & 15, hi = lane >> 4;
    const int wr = wave >> 1, wc = wave & 1;
    const int bn   = blockIdx.x;                    // 0=q, 1=k, 2=v
    const int brow = blockIdx.y * 128;

    const char* Ab = (const char*)As;
    const char* Bb = (const char*)Bs;

    fx4 acc[4][4];
#pragma unroll
    for (int m2 = 0; m2 < 4; m2++)
#pragma unroll
        for (int n = 0; n < 4; n++) acc[m2][n] = fx4{0.f, 0.f, 0.f, 0.f};

    const int arow_s = t >> 4;
    const int acol_s = ((t & 15) ^ ((t >> 4) & 7)) << 2;
    const int brow_s = t >> 3;
    const int bcol_s = ((t & 7) ^ ((t >> 3) & 7)) << 3;
    const int ldsbase = wave * 1024;

    for (int k0 = 0; k0 < EMB; k0 += 64) {
#pragma unroll
        for (int r = 0; r < 8; r++)
            gload16(x + (size_t)(brow + r * 16 + arow_s) * EMB + k0 + acol_s,
                    (char*)As + r * 4096 + ldsbase);
#pragma unroll
        for (int r = 0; r < 4; r++)
            gload16(Wt + (size_t)(bn * 128 + r * 32 + brow_s) * EMB + k0 + bcol_s,
                    (char*)Bs + r * 4096 + ldsbase);
        __syncthreads();

#pragma unroll
        for (int ks = 0; ks < 2; ks++) {
            bf16x8 af[4], bfr[4];
#pragma unroll
            for (int m2 = 0; m2 < 4; m2++) {
                const int rowA = wr * 64 + m2 * 16 + lo;
                const unsigned sw = (rowA & 7) << 4;
                const unsigned ub = rowA * 256 + ks * 128 + hi * 32;
                fx4 a0 = *(const fx4*)(Ab + (ub ^ sw));
                fx4 a1 = *(const fx4*)(Ab + ((ub + 16) ^ sw));
                union { unsigned u[4]; bf16x8 v; } pk;
                pk.u[0] = cvtpk(a0[0], a0[1]);
                pk.u[1] = cvtpk(a0[2], a0[3]);
                pk.u[2] = cvtpk(a1[0], a1[1]);
                pk.u[3] = cvtpk(a1[2], a1[3]);
                af[m2] = pk.v;
            }
#pragma unroll
            for (int n = 0; n < 4; n++) {
                const int rowB = wc * 64 + n * 16 + lo;
                const unsigned ub = rowB * 128 + ks * 64 + hi * 16;
                bfr[n] = *(const bf16x8*)(Bb + (ub ^ ((rowB & 7) << 4)));
            }
#pragma unroll
            for (int m2 = 0; m2 < 4; m2++)
#pragma unroll
                for (int n = 0; n < 4; n++)
                    acc[m2][n] = __builtin_amdgcn_mfma_f32_16x16x32_bf16(af[m2], bfr[n], acc[m2][n], 0, 0, 0);
        }
        __syncthreads();
    }

    const float qscale = 0.03125f;   // 1/sqrt(1024)
#pragma unroll
    for (int m2 = 0; m2 < 4; m2++) {
#pragma unroll
        for (int n = 0; n < 4; n++) {
            const int c = wc * 64 + n * 16 + lo;
#pragma unroll
            for (int j = 0; j < 4; j++) {
                const int r = brow + wr * 64 + m2 * 16 + hi * 4 + j;
                if (bn == 0)      q[(size_t)r * HD + c] = f2bf(acc[m2][n][j] * qscale);
                else if (bn == 1) k[(size_t)r * HD + c] = f2bf(acc[m2][n][j]);
                else {
                    const int bb = r >> 11, cc = r & (CTX - 1);
                    vt[((size_t)bb * HD + c) * VSTR + cc] = f2bf(acc[m2][n][j]);
                }
            }
        }
    }
}

// ---------------- kernel 3: causal flash attention (LDS-staged dbuf) --------
// 256 blocks (1/CU), 2 waves x 16 q-rows. Each block runs TWO q-tiles
// (qt = 63-p then p) -> constant ~34 KV-tiles/block, deterministic balance.
// K[64x128] and Vt[128x64] staged via global_load_lds (16 gload16/thr/tile),
// XOR-swizzled, double-buffered; raw s_barrier + counted vmcnt (never 0
// mid-loop). One batch per XCD.
__global__ __launch_bounds__(128) void attn_kernel(
        const ushort* __restrict__ q, const ushort* __restrict__ k,
        const ushort* __restrict__ vt, float* __restrict__ out) {
    __shared__ __align__(16) char Ks[2][16384];   // [kv 64][hd 128] bf16, swizzled
    __shared__ __align__(16) char Vs[2][16384];   // [h 128][kv 64] bf16, swizzled
    __shared__ __align__(16) char p_lds[2][2048];

    const int id   = blockIdx.x;
    const int b    = id & 7;                      // one batch per XCD
    const int p    = id >> 3;                     // 0..31
    const int t    = threadIdx.x;
    const int wave = t >> 6;
    const int lane = t & 63;
    const int lo = lane & 15, hi = lane >> 4;

    const ushort* qb = q  + (size_t)b * CTX * HD;
    const ushort* kb = k  + (size_t)b * CTX * HD;
    const ushort* vb = vt + (size_t)b * HD * VSTR;

    // staging geometry (16B chunks, XOR-pre-swizzled global source)
    const int krow = t >> 4;                       // + r*8   (K row within tile)
    const int ksl  = ((t & 15) ^ (krow & 7)) << 3; // elems
    const int vrow = t >> 3;                       // + r*16  (V row = head dim)
    const int vsl  = ((t & 7) ^ (vrow & 7)) << 3;  // elems

#define STAGE(bi, kv0_) do {                                                     \
    _Pragma("unroll")                                                            \
    for (int r = 0; r < 8; ++r)                                                  \
        gload16(kb + (size_t)((kv0_) + r * 8 + krow) * HD + ksl,                 \
                Ks[bi] + r * 2048 + wave * 1024);                                \
    _Pragma("unroll")                                                            \
    for (int r = 0; r < 8; ++r)                                                  \
        gload16(vb + (size_t)(r * 16 + vrow) * VSTR + (kv0_) + vsl,              \
                Vs[bi] + r * 2048 + wave * 1024);                                \
} while (0)

    for (int phase = 0; phase < 2; ++phase) {
        const int qt = phase ? p : (63 - p);
        const int q0 = qt * 32 + wave * 16;
        const int nkv = qt / 2 + 1;

        __builtin_amdgcn_s_barrier();   // prev phase fully done (both waves)

        bf16x8 qf[4];
#pragma unroll
        for (int ks = 0; ks < 4; ks++)
            qf[ks] = *(const bf16x8*)(qb + (q0 + lo) * HD + ks * 32 + hi * 8);

        fx4 o[8];
#pragma unroll
        for (int h = 0; h < 8; h++) o[h] = fx4{0.f, 0.f, 0.f, 0.f};
        float m[4], l[4];
#pragma unroll
        for (int j = 0; j < 4; j++) { m[j] = 0.f; l[j] = 0.f; }

        STAGE(0, 0);

        for (int it = 0; it < nkv; ++it) {
            const char* Kb = Ks[it & 1];
            const char* Vb = Vs[it & 1];

            __builtin_amdgcn_s_barrier();              // compute(it-1) done
            if (it + 1 < nkv) {
                STAGE((it + 1) & 1, (it + 1) * 64);
                asm volatile("s_waitcnt vmcnt(16)" ::: "memory");  // stage(it) done
            } else {
                asm volatile("s_waitcnt vmcnt(0)" ::: "memory");
            }
            __builtin_amdgcn_sched_barrier(0);
            __builtin_amdgcn_s_barrier();              // stage(it) visible to all
            __builtin_amdgcn_sched_barrier(0);

            const int kv0 = it * 64;
            const unsigned swz = (unsigned)((lo & 7) << 4);

            // ---- S = Q K^T ----
            fx4 s[4];
#pragma unroll
            for (int n = 0; n < 4; n++) s[n] = fx4{0.f, 0.f, 0.f, 0.f};
            __builtin_amdgcn_s_setprio(1);
#pragma unroll
            for (int n = 0; n < 4; n++) {
                const int row = n * 16 + lo;
#pragma unroll
                for (int ks = 0; ks < 4; ks++) {
                    bf16x8 kf = *(const bf16x8*)(Kb + row * 256 + ((ks * 64 + hi * 16) ^ swz));
                    s[n] = __builtin_amdgcn_mfma_f32_16x16x32_bf16(qf[ks], kf, s[n], 0, 0, 0);
                }
            }
            __builtin_amdgcn_s_setprio(0);

            const bool diag = (kv0 + 64 > q0);
            // ---- mask + defer-max overflow check (lane-local) ----
            float pmax[4];
            int allok = 1;
#pragma unroll
            for (int j = 0; j < 4; j++) {
                const int r = q0 + hi * 4 + j;
                if (diag) {
#pragma unroll
                    for (int n = 0; n < 4; n++)
                        if ((kv0 + n * 16 + lo) > r) s[n][j] = -INFINITY;
                }
                pmax[j] = fmaxf(fmaxf(s[0][j], s[1][j]), fmaxf(s[2][j], s[3][j]));
                allok &= (pmax[j] <= m[j] + 16.0f);
            }
            if (!__all(allok)) {
                // slow path (rare): full cross-lane max + rescale
#pragma unroll
                for (int j = 0; j < 4; j++) {
                    float mx = pmax[j];
                    mx = fmaxf(mx, __shfl_xor(mx, 1));
                    mx = fmaxf(mx, __shfl_xor(mx, 2));
                    mx = fmaxf(mx, __shfl_xor(mx, 4));
                    mx = fmaxf(mx, __shfl_xor(mx, 8));
                    const float mn = fmaxf(m[j], mx);
                    const float f  = __expf(m[j] - mn);
                    l[j] *= f;
#pragma unroll
                    for (int h = 0; h < 8; h++) o[h][j] *= f;
                    m[j] = mn;
                }
            }
            // ---- fast exp + lane-local l + P pack ----
#pragma unroll
            for (int j = 0; j < 4; j++) {
                float sum = 0.f;
#pragma unroll
                for (int n = 0; n < 4; n++) {
                    const float pv = __expf(s[n][j] - m[j]);
                    s[n][j] = pv;
                    sum += pv;
                }
                l[j] += sum;
                const int row = hi * 4 + j;
                const unsigned sw = (row & 7) << 4;
#pragma unroll
                for (int n = 0; n < 4; n++) {
                    const unsigned cb = (unsigned)((n * 16 + lo) * 2);
                    *(ushort*)(p_lds[wave] + row * 128 + (cb ^ sw)) = f2bf(s[n][j]);
                }
            }
            asm volatile("" ::: "memory");
            // ---- PV: A = P (16x64), B = Vt tile ----
            bf16x8 pa[2];
#pragma unroll
            for (int kk = 0; kk < 2; kk++) {
                const unsigned ub = (unsigned)(kk * 64 + hi * 16);
                pa[kk] = *(const bf16x8*)(p_lds[wave] + lo * 128 + (ub ^ swz));
            }
            __builtin_amdgcn_s_setprio(1);
#pragma unroll
            for (int h = 0; h < 8; h++) {
                const int vr = h * 16 + lo;
#pragma unroll
                for (int kk = 0; kk < 2; kk++) {
                    bf16x8 vf = *(const bf16x8*)(Vb + vr * 128 + ((kk * 64 + hi * 16) ^ swz));
                    o[h] = __builtin_amdgcn_mfma_f32_16x16x32_bf16(pa[kk], vf, o[h], 0, 0, 0);
                }
            }
            __builtin_amdgcn_s_setprio(0);
        }

        // ---- cross-lane l reduce + write out ----
#pragma unroll
        for (int j = 0; j < 4; j++) {
            l[j] += __shfl_xor(l[j], 1);
            l[j] += __shfl_xor(l[j], 2);
            l[j] += __shfl_xor(l[j], 4);
            l[j] += __shfl_xor(l[j], 8);
        }
        float* ob = out + ((size_t)b * CTX + q0) * HD;
#pragma unroll
        for (int j = 0; j < 4; j++) {
            const float inv = 1.0f / l[j];
            const int row = hi * 4 + j;
#pragma unroll
            for (int h = 0; h < 8; h++)
                ob[row * HD + h * 16 + lo] = o[h][j] * inv;
        }
    }
#undef STAGE
}

extern "C" void kernel_launch(void* const* d_in, const int* in_sizes, int n_in,
                              void* d_out, int out_size, void* d_ws, size_t ws_size,
                              hipStream_t stream) {
    const float* x  = (const float*)d_in[0];
    const float* Wq = (const float*)d_in[1];
    const float* Wk = (const float*)d_in[2];
    const float* Wv = (const float*)d_in[3];

    // ws: Wt 768KB | q 4MB | k 4MB | Vt (padded) 4.06MB
    ushort* Wt = (ushort*)d_ws;
    ushort* qw = (ushort*)((char*)d_ws + 786432);
    ushort* kw = qw + (size_t)BATCH * CTX * HD;
    ushort* vw = kw + (size_t)BATCH * CTX * HD;

    wt_kernel<<<(3 * HD * EMB) / 256, 256, 0, stream>>>(Wq, Wk, Wv, Wt);
    proj_kernel<<<dim3(3, 128), 256, 0, stream>>>(x, Wt, qw, kw, vw);
    attn_kernel<<<256, 128, 0, stream>>>(qw, kw, vw, (float*)d_out);
}

// Round 6
// 101.786 us; speedup vs baseline: 1.8398x; 1.1436x over previous
//
#include <hip/hip_runtime.h>
#include <hip/hip_bf16.h>

#define BATCH 8
#define CTX   2048
#define EMB   1024
#define HD    128
#define VSTR  2080   // Vt row stride (elems)

using bf16x8 = __attribute__((ext_vector_type(8))) short;
using fx4    = __attribute__((ext_vector_type(4))) float;

__device__ __forceinline__ ushort f2bf(float f) {
    union { float f; unsigned u; } v; v.f = f;
    unsigned u = v.u;
    u += 0x7fffu + ((u >> 16) & 1u);   // RNE
    return (ushort)(u >> 16);
}

__device__ __forceinline__ unsigned cvtpk(float a, float b) {
    unsigned r;
    asm("v_cvt_pk_bf16_f32 %0, %1, %2" : "=v"(r) : "v"(a), "v"(b));
    return r;
}

__device__ __forceinline__ void gload16(const void* g, void* l) {
    __builtin_amdgcn_global_load_lds(
        (const __attribute__((address_space(1))) unsigned*)g,
        (__attribute__((address_space(3))) unsigned*)l, 16, 0, 0);
}

// ---------------- kernel 1: W (E,H) fp32 -> Wt (3,H,E) bf16 ----------------
__global__ void wt_kernel(const float* __restrict__ Wq, const float* __restrict__ Wk,
                          const float* __restrict__ Wv, ushort* __restrict__ Wt) {
    int idx = blockIdx.x * blockDim.x + threadIdx.x;      // [3][HD][EMB]
    int e = idx % EMB;
    int h = (idx / EMB) % HD;
    int w = idx / (EMB * HD);
    const float* W = (w == 0) ? Wq : (w == 1) ? Wk : Wv;
    Wt[idx] = f2bf(W[e * HD + h]);
}

// ---------------- kernel 2: tiled projection GEMM ---------------------------
__global__ __launch_bounds__(256) void proj_kernel(
        const float* __restrict__ x, const ushort* __restrict__ Wt,
        ushort* __restrict__ q, ushort* __restrict__ k, ushort* __restrict__ vt) {
    __shared__ __align__(16) float  As[128 * 64];   // 32 KB
    __shared__ __align__(16) ushort Bs[128 * 64];   // 16 KB

    const int t    = threadIdx.x;
    const int wave = t >> 6;
    const int lane = t & 63;
    const int lo = lane & 15, hi = lane >> 4;
    const int wr = wave >> 1, wc = wave & 1;
    const int bn   = blockIdx.x;                    // 0=q, 1=k, 2=v
    const int brow = blockIdx.y * 128;

    const char* Ab = (const char*)As;
    const char* Bb = (const char*)Bs;

    fx4 acc[4][4];
#pragma unroll
    for (int m2 = 0; m2 < 4; m2++)
#pragma unroll
        for (int n = 0; n < 4; n++) acc[m2][n] = fx4{0.f, 0.f, 0.f, 0.f};

    const int arow_s = t >> 4;
    const int acol_s = ((t & 15) ^ ((t >> 4) & 7)) << 2;
    const int brow_s = t >> 3;
    const int bcol_s = ((t & 7) ^ ((t >> 3) & 7)) << 3;
    const int ldsbase = wave * 1024;

    for (int k0 = 0; k0 < EMB; k0 += 64) {
#pragma unroll
        for (int r = 0; r < 8; r++)
            gload16(x + (size_t)(brow + r * 16 + arow_s) * EMB + k0 + acol_s,
                    (char*)As + r * 4096 + ldsbase);
#pragma unroll
        for (int r = 0; r < 4; r++)
            gload16(Wt + (size_t)(bn * 128 + r * 32 + brow_s) * EMB + k0 + bcol_s,
                    (char*)Bs + r * 4096 + ldsbase);
        __syncthreads();

#pragma unroll
        for (int ks = 0; ks < 2; ks++) {
            bf16x8 af[4], bfr[4];
#pragma unroll
            for (int m2 = 0; m2 < 4; m2++) {
                const int rowA = wr * 64 + m2 * 16 + lo;
                const unsigned sw = (rowA & 7) << 4;
                const unsigned ub = rowA * 256 + ks * 128 + hi * 32;
                fx4 a0 = *(const fx4*)(Ab + (ub ^ sw));
                fx4 a1 = *(const fx4*)(Ab + ((ub + 16) ^ sw));
                union { unsigned u[4]; bf16x8 v; } pk;
                pk.u[0] = cvtpk(a0[0], a0[1]);
                pk.u[1] = cvtpk(a0[2], a0[3]);
                pk.u[2] = cvtpk(a1[0], a1[1]);
                pk.u[3] = cvtpk(a1[2], a1[3]);
                af[m2] = pk.v;
            }
#pragma unroll
            for (int n = 0; n < 4; n++) {
                const int rowB = wc * 64 + n * 16 + lo;
                const unsigned ub = rowB * 128 + ks * 64 + hi * 16;
                bfr[n] = *(const bf16x8*)(Bb + (ub ^ ((rowB & 7) << 4)));
            }
#pragma unroll
            for (int m2 = 0; m2 < 4; m2++)
#pragma unroll
                for (int n = 0; n < 4; n++)
                    acc[m2][n] = __builtin_amdgcn_mfma_f32_16x16x32_bf16(af[m2], bfr[n], acc[m2][n], 0, 0, 0);
        }
        __syncthreads();
    }

    const float qscale = 0.03125f;   // 1/sqrt(1024)
#pragma unroll
    for (int m2 = 0; m2 < 4; m2++) {
#pragma unroll
        for (int n = 0; n < 4; n++) {
            const int c = wc * 64 + n * 16 + lo;
#pragma unroll
            for (int j = 0; j < 4; j++) {
                const int r = brow + wr * 64 + m2 * 16 + hi * 4 + j;
                if (bn == 0)      q[(size_t)r * HD + c] = f2bf(acc[m2][n][j] * qscale);
                else if (bn == 1) k[(size_t)r * HD + c] = f2bf(acc[m2][n][j]);
                else {
                    const int bb = r >> 11, cc = r & (CTX - 1);
                    vt[((size_t)bb * HD + c) * VSTR + cc] = f2bf(acc[m2][n][j]);
                }
            }
        }
    }
}

// ---------------- kernel 3: causal flash attention (KV-col split) -----------
// 1024 blocks x 2 waves = 2048 waves (2/SIMD). Block = one 16-row q-tile;
// the 2 waves split each staged 64-wide KV tile by columns (w*32..w*32+31).
// Single-buffered K/V staging (34KB LDS -> 4 blocks/CU); stage latency hidden
// by co-resident blocks. Defer-max softmax; end merge of 2 partials via LDS.
__global__ __launch_bounds__(128) void attn_kernel(
        const ushort* __restrict__ q, const ushort* __restrict__ k,
        const ushort* __restrict__ vt, float* __restrict__ out) {
    __shared__ __align__(16) char Ks[16384];      // [kv 64][hd 128] bf16, swizzled
    __shared__ __align__(16) char Vs[16384];      // [h 128][kv 64] bf16, swizzled
    __shared__ __align__(16) char p_lds[2][1024]; // per-wave P [16][32] bf16

    const int id   = blockIdx.x;
    const int b    = id & 7;                      // one batch per XCD
    const int pos  = id >> 3;                     // 0..127
    const int qt   = 127 - pos;                   // longest tiles first
    const int q0   = qt * 16;
    const int t    = threadIdx.x;
    const int w    = t >> 6;                      // wave = kv column half
    const int lane = t & 63;
    const int lo = lane & 15, hi = lane >> 4;

    const ushort* qb = q  + (size_t)b * CTX * HD;
    const ushort* kb = k  + (size_t)b * CTX * HD;
    const ushort* vb = vt + (size_t)b * HD * VSTR;

    bf16x8 qf[4];
#pragma unroll
    for (int ks = 0; ks < 4; ks++)
        qf[ks] = *(const bf16x8*)(qb + (q0 + lo) * HD + ks * 32 + hi * 8);

    fx4 o[8];
#pragma unroll
    for (int h = 0; h < 8; h++) o[h] = fx4{0.f, 0.f, 0.f, 0.f};
    float m[4], l[4];
#pragma unroll
    for (int j = 0; j < 4; j++) { m[j] = 0.f; l[j] = 0.f; }

    // staging geometry (16B chunks, XOR-pre-swizzled global source)
    const int krow = t >> 4;                       // + r*8
    const int ksl  = ((t & 15) ^ (krow & 7)) << 3; // elems
    const int vrow = t >> 3;                       // + r*16
    const int vsl  = ((t & 7) ^ (vrow & 7)) << 3;  // elems

    const int nkv = qt / 4 + 1;
    for (int it = 0; it < nkv; ++it) {
        const int kv0 = it * 64;
        __builtin_amdgcn_s_barrier();              // prev tile reads done
#pragma unroll
        for (int r = 0; r < 8; ++r)
            gload16(kb + (size_t)(kv0 + r * 8 + krow) * HD + ksl,
                    Ks + r * 2048 + w * 1024);
#pragma unroll
        for (int r = 0; r < 8; ++r)
            gload16(vb + (size_t)(r * 16 + vrow) * VSTR + kv0 + vsl,
                    Vs + r * 2048 + w * 1024);
        asm volatile("s_waitcnt vmcnt(0)" ::: "memory");
        __builtin_amdgcn_sched_barrier(0);
        __builtin_amdgcn_s_barrier();              // tile visible to both waves
        __builtin_amdgcn_sched_barrier(0);

        // ---- S = Q K^T, this wave's 32 kv columns ----
        fx4 s[2];
        s[0] = fx4{0.f, 0.f, 0.f, 0.f};
        s[1] = fx4{0.f, 0.f, 0.f, 0.f};
        __builtin_amdgcn_s_setprio(1);
#pragma unroll
        for (int n2 = 0; n2 < 2; n2++) {
            const int row = w * 32 + n2 * 16 + lo;
            const unsigned sw = (unsigned)((row & 7) << 4);
#pragma unroll
            for (int ks = 0; ks < 4; ks++) {
                bf16x8 kf = *(const bf16x8*)(Ks + row * 256 + ((ks * 64 + hi * 16) ^ sw));
                s[n2] = __builtin_amdgcn_mfma_f32_16x16x32_bf16(qf[ks], kf, s[n2], 0, 0, 0);
            }
        }
        __builtin_amdgcn_s_setprio(0);

        const bool diag = (kv0 + 64 > q0);
        // ---- mask + defer-max overflow check (lane-local) ----
        float pmax[4];
        int allok = 1;
#pragma unroll
        for (int j = 0; j < 4; j++) {
            const int r = q0 + hi * 4 + j;
            if (diag) {
#pragma unroll
                for (int n2 = 0; n2 < 2; n2++)
                    if ((kv0 + w * 32 + n2 * 16 + lo) > r) s[n2][j] = -INFINITY;
            }
            pmax[j] = fmaxf(s[0][j], s[1][j]);
            allok &= (pmax[j] <= m[j] + 16.0f);
        }
        if (!__all(allok)) {
            // slow path (rare): full cross-lane max + rescale
#pragma unroll
            for (int j = 0; j < 4; j++) {
                float mx = pmax[j];
                mx = fmaxf(mx, __shfl_xor(mx, 1));
                mx = fmaxf(mx, __shfl_xor(mx, 2));
                mx = fmaxf(mx, __shfl_xor(mx, 4));
                mx = fmaxf(mx, __shfl_xor(mx, 8));
                const float mn = fmaxf(m[j], mx);
                const float f  = __expf(m[j] - mn);
                l[j] *= f;
#pragma unroll
                for (int h = 0; h < 8; h++) o[h][j] *= f;
                m[j] = mn;
            }
        }
        // ---- fast exp + lane-local l + P pack ([16][32], swz ^((row&3)<<4)) ----
#pragma unroll
        for (int j = 0; j < 4; j++) {
            float sum = 0.f;
#pragma unroll
            for (int n2 = 0; n2 < 2; n2++) {
                const float pv = __expf(s[n2][j] - m[j]);
                s[n2][j] = pv;
                sum += pv;
            }
            l[j] += sum;
            const int row = hi * 4 + j;
            const unsigned sw = (unsigned)((row & 3) << 4);
#pragma unroll
            for (int n2 = 0; n2 < 2; n2++) {
                const unsigned cb = (unsigned)((n2 * 16 + lo) * 2);
                *(ushort*)(p_lds[w] + row * 64 + (cb ^ sw)) = f2bf(s[n2][j]);
            }
        }
        asm volatile("" ::: "memory");
        // ---- PV: A = P (16x32), B = this wave's Vt half ----
        bf16x8 pa = *(const bf16x8*)(p_lds[w] + lo * 64 + ((hi * 16) ^ ((lo & 3) << 4)));
        __builtin_amdgcn_s_setprio(1);
#pragma unroll
        for (int h = 0; h < 8; h++) {
            const int vr = h * 16 + lo;
            bf16x8 vf = *(const bf16x8*)(Vs + vr * 128 + ((w * 64 + hi * 16) ^ ((vr & 7) << 4)));
            o[h] = __builtin_amdgcn_mfma_f32_16x16x32_bf16(pa, vf, o[h], 0, 0, 0);
        }
        __builtin_amdgcn_s_setprio(0);
    }

    // ---- cross-lane l reduce (16-lane groups) ----
#pragma unroll
    for (int j = 0; j < 4; j++) {
        l[j] += __shfl_xor(l[j], 1);
        l[j] += __shfl_xor(l[j], 2);
        l[j] += __shfl_xor(l[j], 4);
        l[j] += __shfl_xor(l[j], 8);
    }

    // ---- merge the two kv-half partials (reuse Ks/Vs as scratch) ----
    float* oB = (float*)Ks;        // [16][128]
    float* mlB = (float*)Vs;       // [2][16]
    __syncthreads();
    if (w == 1) {
#pragma unroll
        for (int j = 0; j < 4; j++) {
            const int row = hi * 4 + j;
            if (lo == 0) { mlB[row] = m[j]; mlB[16 + row] = l[j]; }
#pragma unroll
            for (int h = 0; h < 8; h++) oB[row * 128 + h * 16 + lo] = o[h][j];
        }
    }
    __syncthreads();
    if (w == 0) {
        float* ob = out + ((size_t)b * CTX + q0) * HD;
#pragma unroll
        for (int j = 0; j < 4; j++) {
            const int row = hi * 4 + j;
            const float mB = mlB[row], lB = mlB[16 + row];
            const float mt = fmaxf(m[j], mB);
            const float fA = __expf(m[j] - mt);
            const float fB = __expf(mB - mt);
            const float inv = 1.0f / (l[j] * fA + lB * fB);
#pragma unroll
            for (int h = 0; h < 8; h++)
                ob[row * HD + h * 16 + lo] =
                    (o[h][j] * fA + oB[row * 128 + h * 16 + lo] * fB) * inv;
        }
    }
}

extern "C" void kernel_launch(void* const* d_in, const int* in_sizes, int n_in,
                              void* d_out, int out_size, void* d_ws, size_t ws_size,
                              hipStream_t stream) {
    const float* x  = (const float*)d_in[0];
    const float* Wq = (const float*)d_in[1];
    const float* Wk = (const float*)d_in[2];
    const float* Wv = (const float*)d_in[3];

    // ws: Wt 768KB | q 4MB | k 4MB | Vt (padded) 4.06MB
    ushort* Wt = (ushort*)d_ws;
    ushort* qw = (ushort*)((char*)d_ws + 786432);
    ushort* kw = qw + (size_t)BATCH * CTX * HD;
    ushort* vw = kw + (size_t)BATCH * CTX * HD;

    wt_kernel<<<(3 * HD * EMB) / 256, 256, 0, stream>>>(Wq, Wk, Wv, Wt);
    proj_kernel<<<dim3(3, 128), 256, 0, stream>>>(x, Wt, qw, kw, vw);
    attn_kernel<<<1024, 128, 0, stream>>>(qw, kw, vw, (float*)d_out);
}

// Round 7
// 100.563 us; speedup vs baseline: 1.8621x; 1.0122x over previous
//
#include <hip/hip_runtime.h>
#include <hip/hip_bf16.h>

#define BATCH 8
#define CTX   2048
#define EMB   1024
#define HD    128
#define VSTR  2080   // Vt row stride (elems)

using bf16x8 = __attribute__((ext_vector_type(8))) short;
using fx4    = __attribute__((ext_vector_type(4))) float;

__device__ __forceinline__ ushort f2bf(float f) {
    union { float f; unsigned u; } v; v.f = f;
    unsigned u = v.u;
    u += 0x7fffu + ((u >> 16) & 1u);   // RNE
    return (ushort)(u >> 16);
}

__device__ __forceinline__ unsigned cvtpk(float a, float b) {
    unsigned r;
    asm("v_cvt_pk_bf16_f32 %0, %1, %2" : "=v"(r) : "v"(a), "v"(b));
    return r;
}

__device__ __forceinline__ void gload16(const void* g, void* l) {
    __builtin_amdgcn_global_load_lds(
        (const __attribute__((address_space(1))) unsigned*)g,
        (__attribute__((address_space(3))) unsigned*)l, 16, 0, 0);
}

// ---------------- kernel 1: W (E,H) fp32 -> Wt (3,H,E) bf16 ----------------
__global__ void wt_kernel(const float* __restrict__ Wq, const float* __restrict__ Wk,
                          const float* __restrict__ Wv, ushort* __restrict__ Wt) {
    int idx = blockIdx.x * blockDim.x + threadIdx.x;      // [3][HD][EMB]
    int e = idx % EMB;
    int h = (idx / EMB) % HD;
    int w = idx / (EMB * HD);
    const float* W = (w == 0) ? Wq : (w == 1) ? Wk : Wv;
    Wt[idx] = f2bf(W[e * HD + h]);
}

// ---------------- kernel 2: fused q/k/v projection (x read ONCE) ------------
// BM=32 rows, BN=384 (q|k|v), BK=32, 512 blocks, 4 waves (each 32x96 cols).
// x staged fp32 [32][128B]; Wt staged [192 rows][128B] = 2 cols x 32 k bf16.
// Double-buffered, counted vmcnt(7). Both LDS reads 2-way (free) after XOR swz.
__global__ __launch_bounds__(256) void proj_kernel(
        const float* __restrict__ x, const ushort* __restrict__ Wt,
        ushort* __restrict__ q, ushort* __restrict__ k, ushort* __restrict__ vt) {
    __shared__ __align__(16) char As[2][4096];    // 8 KB
    __shared__ __align__(16) char Bs[2][24576];   // 48 KB

    const int t    = threadIdx.x;
    const int wave = t >> 6;
    const int lane = t & 63;
    const int lo = lane & 15, hi = lane >> 4;
    const int brow = blockIdx.x * 32;

    fx4 acc[2][6];
#pragma unroll
    for (int m2 = 0; m2 < 2; m2++)
#pragma unroll
        for (int n = 0; n < 6; n++) acc[m2][n] = fx4{0.f, 0.f, 0.f, 0.f};

    // staging sources (XOR-pre-swizzled global addresses; LDS dest linear)
    const int arow  = t >> 3;                      // 0..31
    const int aslot = (t & 7) ^ (arow & 7);
    const float* asrc = x + (size_t)(brow + arow) * EMB + aslot * 4;

    const ushort* bsrc[6];
#pragma unroll
    for (int r = 0; r < 6; r++) {
        const int lrow = r * 32 + (t >> 3);        // 0..191 (= col pair)
        const int u    = (t & 7) ^ (lrow & 7);     // unswizzled slot
        bsrc[r] = Wt + (size_t)(lrow * 2 + (u >> 2)) * EMB + (u & 3) * 8;
    }

#define PSTAGE(bi, k0_) do {                                          \
    gload16(asrc + (k0_), As[bi] + wave * 1024);                      \
    _Pragma("unroll")                                                 \
    for (int r = 0; r < 6; ++r)                                       \
        gload16(bsrc[r] + (k0_), Bs[bi] + r * 4096 + wave * 1024);    \
} while (0)

    PSTAGE(0, 0);
    for (int it = 0; it < 32; ++it) {
        if (it + 1 < 32) {
            PSTAGE((it + 1) & 1, (it + 1) * 32);
            asm volatile("s_waitcnt vmcnt(7)" ::: "memory");   // stage(it) done
        } else {
            asm volatile("s_waitcnt vmcnt(0)" ::: "memory");
        }
        __builtin_amdgcn_sched_barrier(0);
        __builtin_amdgcn_s_barrier();
        __builtin_amdgcn_sched_barrier(0);

        const char* Ab = As[it & 1];
        const char* Bb = Bs[it & 1];

        bf16x8 af[2];
#pragma unroll
        for (int m2 = 0; m2 < 2; m2++) {
            const int rowA = m2 * 16 + lo;
            const int s0 = (hi * 2) ^ (rowA & 7);
            const int s1 = (hi * 2 + 1) ^ (rowA & 7);
            fx4 a0 = *(const fx4*)(Ab + rowA * 128 + s0 * 16);
            fx4 a1 = *(const fx4*)(Ab + rowA * 128 + s1 * 16);
            union { unsigned u[4]; bf16x8 v; } pk;
            pk.u[0] = cvtpk(a0[0], a0[1]);
            pk.u[1] = cvtpk(a0[2], a0[3]);
            pk.u[2] = cvtpk(a1[0], a1[1]);
            pk.u[3] = cvtpk(a1[2], a1[3]);
            af[m2] = pk.v;
        }
        __builtin_amdgcn_s_setprio(1);
#pragma unroll
        for (int n = 0; n < 6; n++) {
            const int col  = wave * 96 + n * 16 + lo;
            const int rowp = col >> 1;
            const int slot = ((col & 1) * 4 + hi) ^ (rowp & 7);
            bf16x8 bfr = *(const bf16x8*)(Bb + rowp * 128 + slot * 16);
#pragma unroll
            for (int m2 = 0; m2 < 2; m2++)
                acc[m2][n] = __builtin_amdgcn_mfma_f32_16x16x32_bf16(af[m2], bfr, acc[m2][n], 0, 0, 0);
        }
        __builtin_amdgcn_s_setprio(0);
        __builtin_amdgcn_s_barrier();   // both-wave reads done before overwrite
    }
#undef PSTAGE

    const float qscale = 0.03125f;   // 1/sqrt(1024)
#pragma unroll
    for (int n = 0; n < 6; n++) {
        const int col = wave * 96 + n * 16 + lo;
        const int bnn = col >> 7;
        const int cc  = col & 127;
#pragma unroll
        for (int m2 = 0; m2 < 2; m2++) {
#pragma unroll
            for (int j = 0; j < 4; j++) {
                const int r = brow + m2 * 16 + hi * 4 + j;
                if (bnn == 0)      q[(size_t)r * HD + cc] = f2bf(acc[m2][n][j] * qscale);
                else if (bnn == 1) k[(size_t)r * HD + cc] = f2bf(acc[m2][n][j]);
                else {
                    const int bb = r >> 11, ccc = r & (CTX - 1);
                    vt[((size_t)bb * HD + cc) * VSTR + ccc] = f2bf(acc[m2][n][j]);
                }
            }
        }
    }
}

// ---------------- kernel 3: causal flash attention (KV-col split, dbuf) -----
// 1024 blocks x 2 waves; block = one 16-row q-tile, waves split each 64-wide
// KV tile by columns. K/V double-buffered in LDS via global_load_lds with
// counted vmcnt(16). Defer-max softmax; end merge of 2 partials via LDS.
__global__ __launch_bounds__(128) void attn_kernel(
        const ushort* __restrict__ q, const ushort* __restrict__ k,
        const ushort* __restrict__ vt, float* __restrict__ out) {
    __shared__ __align__(16) char Ks[2][16384];   // [kv 64][hd 128] bf16, swizzled
    __shared__ __align__(16) char Vs[2][16384];   // [h 128][kv 64] bf16, swizzled
    __shared__ __align__(16) char p_lds[2][1024]; // per-wave P [16][32] bf16

    const int id   = blockIdx.x;
    const int b    = id & 7;                      // one batch per XCD
    const int pos  = id >> 3;                     // 0..127
    const int qt   = 127 - pos;                   // longest tiles first
    const int q0   = qt * 16;
    const int t    = threadIdx.x;
    const int w    = t >> 6;                      // wave = kv column half
    const int lane = t & 63;
    const int lo = lane & 15, hi = lane >> 4;

    const ushort* qb = q  + (size_t)b * CTX * HD;
    const ushort* kb = k  + (size_t)b * CTX * HD;
    const ushort* vb = vt + (size_t)b * HD * VSTR;

    bf16x8 qf[4];
#pragma unroll
    for (int ks = 0; ks < 4; ks++)
        qf[ks] = *(const bf16x8*)(qb + (q0 + lo) * HD + ks * 32 + hi * 8);

    fx4 o[8];
#pragma unroll
    for (int h = 0; h < 8; h++) o[h] = fx4{0.f, 0.f, 0.f, 0.f};
    float m[4], l[4];
#pragma unroll
    for (int j = 0; j < 4; j++) { m[j] = 0.f; l[j] = 0.f; }

    // staging geometry (16B chunks, XOR-pre-swizzled global source)
    const int krow = t >> 4;
    const int ksl  = ((t & 15) ^ (krow & 7)) << 3;
    const int vrow = t >> 3;
    const int vsl  = ((t & 7) ^ (vrow & 7)) << 3;

#define STAGE(bi, kv0_) do {                                          \
    _Pragma("unroll")                                                 \
    for (int r = 0; r < 8; ++r)                                       \
        gload16(kb + (size_t)((kv0_) + r * 8 + krow) * HD + ksl,      \
                Ks[bi] + r * 2048 + w * 1024);                        \
    _Pragma("unroll")                                                 \
    for (int r = 0; r < 8; ++r)                                       \
        gload16(vb + (size_t)(r * 16 + vrow) * VSTR + (kv0_) + vsl,   \
                Vs[bi] + r * 2048 + w * 1024);                        \
} while (0)

    const int nkv = qt / 4 + 1;
    STAGE(0, 0);
    for (int it = 0; it < nkv; ++it) {
        if (it + 1 < nkv) {
            STAGE((it + 1) & 1, (it + 1) * 64);
            asm volatile("s_waitcnt vmcnt(16)" ::: "memory");  // stage(it) done
        } else {
            asm volatile("s_waitcnt vmcnt(0)" ::: "memory");
        }
        __builtin_amdgcn_sched_barrier(0);
        __builtin_amdgcn_s_barrier();              // tile it visible to both waves
        __builtin_amdgcn_sched_barrier(0);

        const char* Kb = Ks[it & 1];
        const char* Vb = Vs[it & 1];
        const int kv0 = it * 64;

        // ---- S = Q K^T, this wave's 32 kv columns ----
        fx4 s[2];
        s[0] = fx4{0.f, 0.f, 0.f, 0.f};
        s[1] = fx4{0.f, 0.f, 0.f, 0.f};
        __builtin_amdgcn_s_setprio(1);
#pragma unroll
        for (int n2 = 0; n2 < 2; n2++) {
            const int row = w * 32 + n2 * 16 + lo;
            const unsigned sw = (unsigned)((row & 7) << 4);
#pragma unroll
            for (int ks = 0; ks < 4; ks++) {
                bf16x8 kf = *(const bf16x8*)(Kb + row * 256 + ((ks * 64 + hi * 16) ^ sw));
                s[n2] = __builtin_amdgcn_mfma_f32_16x16x32_bf16(qf[ks], kf, s[n2], 0, 0, 0);
            }
        }
        __builtin_amdgcn_s_setprio(0);

        const bool diag = (kv0 + 64 > q0);
        // ---- mask + defer-max overflow check (lane-local) ----
        float pmax[4];
        int allok = 1;
#pragma unroll
        for (int j = 0; j < 4; j++) {
            const int r = q0 + hi * 4 + j;
            if (diag) {
#pragma unroll
                for (int n2 = 0; n2 < 2; n2++)
                    if ((kv0 + w * 32 + n2 * 16 + lo) > r) s[n2][j] = -INFINITY;
            }
            pmax[j] = fmaxf(s[0][j], s[1][j]);
            allok &= (pmax[j] <= m[j] + 16.0f);
        }
        if (!__all(allok)) {
            // slow path (rare): full cross-lane max + rescale
#pragma unroll
            for (int j = 0; j < 4; j++) {
                float mx = pmax[j];
                mx = fmaxf(mx, __shfl_xor(mx, 1));
                mx = fmaxf(mx, __shfl_xor(mx, 2));
                mx = fmaxf(mx, __shfl_xor(mx, 4));
                mx = fmaxf(mx, __shfl_xor(mx, 8));
                const float mn = fmaxf(m[j], mx);
                const float f  = __expf(m[j] - mn);
                l[j] *= f;
#pragma unroll
                for (int h = 0; h < 8; h++) o[h][j] *= f;
                m[j] = mn;
            }
        }
        // ---- fast exp + lane-local l + P pack ----
#pragma unroll
        for (int j = 0; j < 4; j++) {
            float sum = 0.f;
#pragma unroll
            for (int n2 = 0; n2 < 2; n2++) {
                const float pv = __expf(s[n2][j] - m[j]);
                s[n2][j] = pv;
                sum += pv;
            }
            l[j] += sum;
            const int row = hi * 4 + j;
            const unsigned sw = (unsigned)((row & 3) << 4);
#pragma unroll
            for (int n2 = 0; n2 < 2; n2++) {
                const unsigned cb = (unsigned)((n2 * 16 + lo) * 2);
                *(ushort*)(p_lds[w] + row * 64 + (cb ^ sw)) = f2bf(s[n2][j]);
            }
        }
        asm volatile("" ::: "memory");
        // ---- PV: A = P (16x32), B = this wave's Vt half ----
        bf16x8 pa = *(const bf16x8*)(p_lds[w] + lo * 64 + ((hi * 16) ^ ((lo & 3) << 4)));
        __builtin_amdgcn_s_setprio(1);
#pragma unroll
        for (int h = 0; h < 8; h++) {
            const int vr = h * 16 + lo;
            bf16x8 vf = *(const bf16x8*)(Vb + vr * 128 + ((w * 64 + hi * 16) ^ ((vr & 7) << 4)));
            o[h] = __builtin_amdgcn_mfma_f32_16x16x32_bf16(pa, vf, o[h], 0, 0, 0);
        }
        __builtin_amdgcn_s_setprio(0);
        __builtin_amdgcn_s_barrier();              // both waves done reading tile it
    }
#undef STAGE

    // ---- cross-lane l reduce (16-lane groups) ----
#pragma unroll
    for (int j = 0; j < 4; j++) {
        l[j] += __shfl_xor(l[j], 1);
        l[j] += __shfl_xor(l[j], 2);
        l[j] += __shfl_xor(l[j], 4);
        l[j] += __shfl_xor(l[j], 8);
    }

    // ---- merge the two kv-half partials (reuse Ks as scratch) ----
    float* oB  = (float*)Ks[0];    // [16][128]
    float* mlB = (float*)Vs[0];    // [2][16]
    __syncthreads();
    if (w == 1) {
#pragma unroll
        for (int j = 0; j < 4; j++) {
            const int row = hi * 4 + j;
            if (lo == 0) { mlB[row] = m[j]; mlB[16 + row] = l[j]; }
#pragma unroll
            for (int h = 0; h < 8; h++) oB[row * 128 + h * 16 + lo] = o[h][j];
        }
    }
    __syncthreads();
    if (w == 0) {
        float* ob = out + ((size_t)b * CTX + q0) * HD;
#pragma unroll
        for (int j = 0; j < 4; j++) {
            const int row = hi * 4 + j;
            const float mB = mlB[row], lB = mlB[16 + row];
            const float mt = fmaxf(m[j], mB);
            const float fA = __expf(m[j] - mt);
            const float fB = __expf(mB - mt);
            const float inv = 1.0f / (l[j] * fA + lB * fB);
#pragma unroll
            for (int h = 0; h < 8; h++)
                ob[row * HD + h * 16 + lo] =
                    (o[h][j] * fA + oB[row * 128 + h * 16 + lo] * fB) * inv;
        }
    }
}

extern "C" void kernel_launch(void* const* d_in, const int* in_sizes, int n_in,
                              void* d_out, int out_size, void* d_ws, size_t ws_size,
                              hipStream_t stream) {
    const float* x  = (const float*)d_in[0];
    const float* Wq = (const float*)d_in[1];
    const float* Wk = (const float*)d_in[2];
    const float* Wv = (const float*)d_in[3];

    // ws: Wt 768KB | q 4MB | k 4MB | Vt (padded) 4.06MB
    ushort* Wt = (ushort*)d_ws;
    ushort* qw = (ushort*)((char*)d_ws + 786432);
    ushort* kw = qw + (size_t)BATCH * CTX * HD;
    ushort* vw = kw + (size_t)BATCH * CTX * HD;

    wt_kernel<<<(3 * HD * EMB) / 256, 256, 0, stream>>>(Wq, Wk, Wv, Wt);
    proj_kernel<<<(BATCH * CTX) / 32, 256, 0, stream>>>(x, Wt, qw, kw, vw);
    attn_kernel<<<1024, 128, 0, stream>>>(qw, kw, vw, (float*)d_out);
}

// Round 8
// 96.833 us; speedup vs baseline: 1.9339x; 1.0385x over previous
//
#include <hip/hip_runtime.h>
#include <hip/hip_bf16.h>

#define BATCH 8
#define CTX   2048
#define EMB   1024
#define HD    128
#define VSTR  2080   // Vt row stride (elems)

using bf16x8 = __attribute__((ext_vector_type(8))) short;
using fx4    = __attribute__((ext_vector_type(4))) float;

__device__ __forceinline__ ushort f2bf(float f) {
    union { float f; unsigned u; } v; v.f = f;
    unsigned u = v.u;
    u += 0x7fffu + ((u >> 16) & 1u);   // RNE
    return (ushort)(u >> 16);
}

__device__ __forceinline__ unsigned cvtpk(float a, float b) {
    unsigned r;
    asm("v_cvt_pk_bf16_f32 %0, %1, %2" : "=v"(r) : "v"(a), "v"(b));
    return r;
}

__device__ __forceinline__ void gload16(const void* g, void* l) {
    __builtin_amdgcn_global_load_lds(
        (const __attribute__((address_space(1))) unsigned*)g,
        (__attribute__((address_space(3))) unsigned*)l, 16, 0, 0);
}

// ---------------- kernel 1: W (E,H) fp32 -> Wt (3,H,E) bf16 ----------------
__global__ void wt_kernel(const float* __restrict__ Wq, const float* __restrict__ Wk,
                          const float* __restrict__ Wv, ushort* __restrict__ Wt) {
    int idx = blockIdx.x * blockDim.x + threadIdx.x;      // [3][HD][EMB]
    int e = idx % EMB;
    int h = (idx / EMB) % HD;
    int w = idx / (EMB * HD);
    const float* W = (w == 0) ? Wq : (w == 1) ? Wk : Wv;
    Wt[idx] = f2bf(W[e * HD + h]);
}

// ---------------- kernel 2: fused q/k/v projection (x read ONCE) ------------
// BM=32, BN=384 (q|k|v), BK=32, 512 blocks, 4 waves (each 32x96 cols).
// A (HBM-sourced) triple-buffered with 2-iter prefetch depth; B (L2-hot Wt)
// double-buffered 1-iter. Issue order B-then-A => FIFO vmcnt(1) leaves only
// A(it+2) outstanding. ONE barrier per K-step (stage-after-barrier is safe).
__global__ __launch_bounds__(256) void proj_kernel(
        const float* __restrict__ x, const ushort* __restrict__ Wt,
        ushort* __restrict__ q, ushort* __restrict__ k, ushort* __restrict__ vt) {
    __shared__ __align__(16) char As[3][4096];    // 12 KB
    __shared__ __align__(16) char Bs[2][24576];   // 48 KB

    const int t    = threadIdx.x;
    const int wave = t >> 6;
    const int lane = t & 63;
    const int lo = lane & 15, hi = lane >> 4;
    const int brow = blockIdx.x * 32;

    fx4 acc[2][6];
#pragma unroll
    for (int m2 = 0; m2 < 2; m2++)
#pragma unroll
        for (int n = 0; n < 6; n++) acc[m2][n] = fx4{0.f, 0.f, 0.f, 0.f};

    // staging sources (XOR-pre-swizzled global addresses; LDS dest linear)
    const int arow  = t >> 3;                      // 0..31
    const int aslot = (t & 7) ^ (arow & 7);
    const float* asrc = x + (size_t)(brow + arow) * EMB + aslot * 4;

    const ushort* bsrc[6];
#pragma unroll
    for (int r = 0; r < 6; r++) {
        const int lrow = r * 32 + (t >> 3);        // 0..191 (= col pair)
        const int u    = (t & 7) ^ (lrow & 7);     // unswizzled slot
        bsrc[r] = Wt + (size_t)(lrow * 2 + (u >> 2)) * EMB + (u & 3) * 8;
    }

    // prologue: A(0), B(0), A(1)  (A(1) newest -> vmcnt(1) at it=0 leaves it)
    gload16(asrc + 0, As[0] + wave * 1024);
#pragma unroll
    for (int r = 0; r < 6; ++r)
        gload16(bsrc[r] + 0, Bs[0] + r * 4096 + wave * 1024);
    gload16(asrc + 32, As[1] + wave * 1024);

    for (int it = 0; it < 32; ++it) {
        if (it == 31) asm volatile("s_waitcnt vmcnt(0)" ::: "memory");
        else          asm volatile("s_waitcnt vmcnt(1)" ::: "memory");
        __builtin_amdgcn_sched_barrier(0);
        __builtin_amdgcn_s_barrier();
        __builtin_amdgcn_sched_barrier(0);

        // stage next: B(it+1) first, A(it+2) last (FIFO order)
        if (it + 1 < 32) {
#pragma unroll
            for (int r = 0; r < 6; ++r)
                gload16(bsrc[r] + (it + 1) * 32, Bs[(it + 1) & 1] + r * 4096 + wave * 1024);
            if (it + 2 < 32)
                gload16(asrc + (it + 2) * 32, As[(it + 2) % 3] + wave * 1024);
        }

        const char* Ab = As[it % 3];
        const char* Bb = Bs[it & 1];

        bf16x8 af[2];
#pragma unroll
        for (int m2 = 0; m2 < 2; m2++) {
            const int rowA = m2 * 16 + lo;
            const int s0 = (hi * 2) ^ (rowA & 7);
            const int s1 = (hi * 2 + 1) ^ (rowA & 7);
            fx4 a0 = *(const fx4*)(Ab + rowA * 128 + s0 * 16);
            fx4 a1 = *(const fx4*)(Ab + rowA * 128 + s1 * 16);
            union { unsigned u[4]; bf16x8 v; } pk;
            pk.u[0] = cvtpk(a0[0], a0[1]);
            pk.u[1] = cvtpk(a0[2], a0[3]);
            pk.u[2] = cvtpk(a1[0], a1[1]);
            pk.u[3] = cvtpk(a1[2], a1[3]);
            af[m2] = pk.v;
        }
        __builtin_amdgcn_s_setprio(1);
#pragma unroll
        for (int n = 0; n < 6; n++) {
            const int col  = wave * 96 + n * 16 + lo;
            const int rowp = col >> 1;
            const int slot = ((col & 1) * 4 + hi) ^ (rowp & 7);
            bf16x8 bfr = *(const bf16x8*)(Bb + rowp * 128 + slot * 16);
#pragma unroll
            for (int m2 = 0; m2 < 2; m2++)
                acc[m2][n] = __builtin_amdgcn_mfma_f32_16x16x32_bf16(af[m2], bfr, acc[m2][n], 0, 0, 0);
        }
        __builtin_amdgcn_s_setprio(0);
    }

    const float qscale = 0.03125f;   // 1/sqrt(1024)
#pragma unroll
    for (int n = 0; n < 6; n++) {
        const int col = wave * 96 + n * 16 + lo;
        const int bnn = col >> 7;
        const int cc  = col & 127;
#pragma unroll
        for (int m2 = 0; m2 < 2; m2++) {
#pragma unroll
            for (int j = 0; j < 4; j++) {
                const int r = brow + m2 * 16 + hi * 4 + j;
                if (bnn == 0)      q[(size_t)r * HD + cc] = f2bf(acc[m2][n][j] * qscale);
                else if (bnn == 1) k[(size_t)r * HD + cc] = f2bf(acc[m2][n][j]);
                else {
                    const int bb = r >> 11, ccc = r & (CTX - 1);
                    vt[((size_t)bb * HD + cc) * VSTR + ccc] = f2bf(acc[m2][n][j]);
                }
            }
        }
    }
}

// ---------------- kernel 3: causal flash attention (32 q-rows, 4 waves) -----
// 512 blocks x 4 waves = 2048 waves (2/SIMD, 2 blocks/CU). wq = q 16-row
// group, w = kv column half. K/V dbuf staged via global_load_lds; single
// barrier per tile (stage-after-barrier). Defer-max softmax; LDS merge.
__global__ __launch_bounds__(256) void attn_kernel(
        const ushort* __restrict__ q, const ushort* __restrict__ k,
        const ushort* __restrict__ vt, float* __restrict__ out) {
    __shared__ __align__(16) char Ks[2][16384];   // [kv 64][hd 128] bf16, swizzled
    __shared__ __align__(16) char Vs[2][16384];   // [h 128][kv 64] bf16, swizzled
    __shared__ __align__(16) char p_lds[4][1024]; // per-wave P [16][32] bf16

    const int id   = blockIdx.x;
    const int b    = id & 7;                      // one batch per XCD
    const int pos  = id >> 3;                     // 0..63
    const int qt   = (pos < 32) ? (63 - pos) : (pos - 32);  // serpentine balance
    const int t    = threadIdx.x;
    const int wave = t >> 6;
    const int lane = t & 63;
    const int lo = lane & 15, hi = lane >> 4;
    const int wq = wave & 1, w = wave >> 1;
    const int q0 = qt * 32 + wq * 16;

    const ushort* qb = q  + (size_t)b * CTX * HD;
    const ushort* kb = k  + (size_t)b * CTX * HD;
    const ushort* vb = vt + (size_t)b * HD * VSTR;

    bf16x8 qf[4];
#pragma unroll
    for (int ks = 0; ks < 4; ks++)
        qf[ks] = *(const bf16x8*)(qb + (q0 + lo) * HD + ks * 32 + hi * 8);

    fx4 o[8];
#pragma unroll
    for (int h = 0; h < 8; h++) o[h] = fx4{0.f, 0.f, 0.f, 0.f};
    float m[4], l[4];
#pragma unroll
    for (int j = 0; j < 4; j++) { m[j] = 0.f; l[j] = 0.f; }

#define STAGE(bi, kv0_) do {                                                   \
    _Pragma("unroll")                                                          \
    for (int r = 0; r < 4; ++r) {                                              \
        const int row = r * 16 + (t >> 4);                                     \
        gload16(kb + (size_t)((kv0_) + row) * HD + (((t & 15) ^ (row & 7)) << 3), \
                Ks[bi] + r * 4096 + wave * 1024);                              \
    }                                                                          \
    _Pragma("unroll")                                                          \
    for (int r = 0; r < 4; ++r) {                                              \
        const int row = r * 32 + (t >> 3);                                     \
        gload16(vb + (size_t)row * VSTR + (kv0_) + (((t & 7) ^ (row & 7)) << 3), \
                Vs[bi] + r * 4096 + wave * 1024);                              \
    }                                                                          \
} while (0)

    const int nkv = qt / 2 + 1;
    STAGE(0, 0);
    for (int it = 0; it < nkv; ++it) {
        asm volatile("s_waitcnt vmcnt(0)" ::: "memory");   // stage(it) done
        __builtin_amdgcn_sched_barrier(0);
        __builtin_amdgcn_s_barrier();                      // visible to all waves
        __builtin_amdgcn_sched_barrier(0);
        if (it + 1 < nkv) STAGE((it + 1) & 1, (it + 1) * 64);

        const char* Kb = Ks[it & 1];
        const char* Vb = Vs[it & 1];
        const int kv0 = it * 64;

        // ---- S = Q K^T, this wave's 32 kv columns ----
        fx4 s[2];
        s[0] = fx4{0.f, 0.f, 0.f, 0.f};
        s[1] = fx4{0.f, 0.f, 0.f, 0.f};
        __builtin_amdgcn_s_setprio(1);
#pragma unroll
        for (int n2 = 0; n2 < 2; n2++) {
            const int row = w * 32 + n2 * 16 + lo;
            const unsigned sw = (unsigned)((row & 7) << 4);
#pragma unroll
            for (int ks = 0; ks < 4; ks++) {
                bf16x8 kf = *(const bf16x8*)(Kb + row * 256 + ((ks * 64 + hi * 16) ^ sw));
                s[n2] = __builtin_amdgcn_mfma_f32_16x16x32_bf16(qf[ks], kf, s[n2], 0, 0, 0);
            }
        }
        __builtin_amdgcn_s_setprio(0);

        const bool diag = (kv0 + 64 > q0);
        // ---- mask + defer-max overflow check (lane-local) ----
        float pmax[4];
        int allok = 1;
#pragma unroll
        for (int j = 0; j < 4; j++) {
            const int r = q0 + hi * 4 + j;
            if (diag) {
#pragma unroll
                for (int n2 = 0; n2 < 2; n2++)
                    if ((kv0 + w * 32 + n2 * 16 + lo) > r) s[n2][j] = -INFINITY;
            }
            pmax[j] = fmaxf(s[0][j], s[1][j]);
            allok &= (pmax[j] <= m[j] + 16.0f);
        }
        if (!__all(allok)) {
            // slow path (rare): full cross-lane max + rescale
#pragma unroll
            for (int j = 0; j < 4; j++) {
                float mx = pmax[j];
                mx = fmaxf(mx, __shfl_xor(mx, 1));
                mx = fmaxf(mx, __shfl_xor(mx, 2));
                mx = fmaxf(mx, __shfl_xor(mx, 4));
                mx = fmaxf(mx, __shfl_xor(mx, 8));
                const float mn = fmaxf(m[j], mx);
                const float f  = __expf(m[j] - mn);
                l[j] *= f;
#pragma unroll
                for (int h = 0; h < 8; h++) o[h][j] *= f;
                m[j] = mn;
            }
        }
        // ---- fast exp + lane-local l + P pack ----
#pragma unroll
        for (int j = 0; j < 4; j++) {
            float sum = 0.f;
#pragma unroll
            for (int n2 = 0; n2 < 2; n2++) {
                const float pv = __expf(s[n2][j] - m[j]);
                s[n2][j] = pv;
                sum += pv;
            }
            l[j] += sum;
            const int row = hi * 4 + j;
            const unsigned sw = (unsigned)((row & 3) << 4);
#pragma unroll
            for (int n2 = 0; n2 < 2; n2++) {
                const unsigned cb = (unsigned)((n2 * 16 + lo) * 2);
                *(ushort*)(p_lds[wave] + row * 64 + (cb ^ sw)) = f2bf(s[n2][j]);
            }
        }
        asm volatile("" ::: "memory");
        // ---- PV: A = P (16x32), B = this wave's Vt col half ----
        bf16x8 pa = *(const bf16x8*)(p_lds[wave] + lo * 64 + ((hi * 16) ^ ((lo & 3) << 4)));
        __builtin_amdgcn_s_setprio(1);
#pragma unroll
        for (int h = 0; h < 8; h++) {
            const int vr = h * 16 + lo;
            bf16x8 vf = *(const bf16x8*)(Vb + vr * 128 + ((w * 64 + hi * 16) ^ ((vr & 7) << 4)));
            o[h] = __builtin_amdgcn_mfma_f32_16x16x32_bf16(pa, vf, o[h], 0, 0, 0);
        }
        __builtin_amdgcn_s_setprio(0);
    }
#undef STAGE

    // ---- cross-lane l reduce (16-lane groups) ----
#pragma unroll
    for (int j = 0; j < 4; j++) {
        l[j] += __shfl_xor(l[j], 1);
        l[j] += __shfl_xor(l[j], 2);
        l[j] += __shfl_xor(l[j], 4);
        l[j] += __shfl_xor(l[j], 8);
    }

    // ---- merge the two kv-half partials per q-group (reuse Ks/Vs) ----
    float* oB  = (float*)Ks[0];    // [2][16][128]
    float* mlB = (float*)Vs[0];    // [2][2][16]
    __syncthreads();
    if (w == 1) {
#pragma unroll
        for (int j = 0; j < 4; j++) {
            const int row = hi * 4 + j;
            if (lo == 0) { mlB[wq * 32 + row] = m[j]; mlB[wq * 32 + 16 + row] = l[j]; }
#pragma unroll
            for (int h = 0; h < 8; h++)
                oB[(wq * 16 + row) * 128 + h * 16 + lo] = o[h][j];
        }
    }
    __syncthreads();
    if (w == 0) {
        float* ob = out + ((size_t)b * CTX + q0) * HD;
#pragma unroll
        for (int j = 0; j < 4; j++) {
            const int row = hi * 4 + j;
            const float mB = mlB[wq * 32 + row], lB = mlB[wq * 32 + 16 + row];
            const float mt = fmaxf(m[j], mB);
            const float fA = __expf(m[j] - mt);
            const float fB = __expf(mB - mt);
            const float inv = 1.0f / (l[j] * fA + lB * fB);
#pragma unroll
            for (int h = 0; h < 8; h++)
                ob[row * HD + h * 16 + lo] =
                    (o[h][j] * fA + oB[(wq * 16 + row) * 128 + h * 16 + lo] * fB) * inv;
        }
    }
}

extern "C" void kernel_launch(void* const* d_in, const int* in_sizes, int n_in,
                              void* d_out, int out_size, void* d_ws, size_t ws_size,
                              hipStream_t stream) {
    const float* x  = (const float*)d_in[0];
    const float* Wq = (const float*)d_in[1];
    const float* Wk = (const float*)d_in[2];
    const float* Wv = (const float*)d_in[3];

    // ws: Wt 768KB | q 4MB | k 4MB | Vt (padded) 4.06MB
    ushort* Wt = (ushort*)d_ws;
    ushort* qw = (ushort*)((char*)d_ws + 786432);
    ushort* kw = qw + (size_t)BATCH * CTX * HD;
    ushort* vw = kw + (size_t)BATCH * CTX * HD;

    wt_kernel<<<(3 * HD * EMB) / 256, 256, 0, stream>>>(Wq, Wk, Wv, Wt);
    proj_kernel<<<(BATCH * CTX) / 32, 256, 0, stream>>>(x, Wt, qw, kw, vw);
    attn_kernel<<<512, 256, 0, stream>>>(qw, kw, vw, (float*)d_out);
}